// Round 10
// baseline (466.537 us; speedup 1.0000x reference)
//
#include <hip/hip_runtime.h>
#include <stdint.h>

// GoalDecoderLSTM: B=131072 indep LSTM decoders, H=64, E=16, SEQ=30. f32 I/O.
// R16: pair-split breadth (spill-free). R15 post-mortem: full acc[4][4]
// breadth spilled (WRITE_SIZE 30.7->47MB, the pre-registered canary) and
// regressed 350->364; the breadth idea was never tested at legal register
// pressure. Fix: slice PAIRS -- per step, twice: {24 MFMAs -> acc[2][4]
// (32 regs); 2 slices' nonlin; 2 b64 writes}. Phase 1 has 8 indep 3-MFMA
// chains, phase 2 has 4 indep f32x2 exp2 streams (vs R14's 4/2), peak live
// ~= 56 arch + 32 acc + transients ~ 100 < 128 cap -> no spill. Pair-0's
// h-writes precede pair-1's MFMAs (wider write->read distance to next
// step's ds_read). Everything else identical to R14.
// Session ranking: R13 342 < R14 348 < R15 364 (spill) -- LDS layout is
// not the binding constraint; issue/dependency structure is.
// Kept: autonomous waves (zero loop barriers), frag-major conflict-free
// weights, operand-swapped gates (D[hidden][batch], b64 h-writeback),
// prescaled gate weights (-log2e/+2log2e), lrelu rank-2 fold (kx 16..18),
// all-quad rel, f32x2 nonlinearity + pair-rcp.

#define B_TOT 131072
#define SEQL 30
#define WPB 8  // waves per block = tiles per block

typedef _Float16 f16x8 __attribute__((ext_vector_type(8)));
typedef _Float16 f16x4 __attribute__((ext_vector_type(4)));
typedef _Float16 f16x2 __attribute__((ext_vector_type(2)));
typedef float f32x4 __attribute__((ext_vector_type(4)));
typedef float f32x2 __attribute__((ext_vector_type(2)));

__device__ __forceinline__ float fexp2(float x) {
#if __has_builtin(__builtin_amdgcn_exp2f)
  return __builtin_amdgcn_exp2f(x);
#else
  return exp2f(x);
#endif
}
__device__ __forceinline__ float frcp(float x) {
#if __has_builtin(__builtin_amdgcn_rcpf)
  return __builtin_amdgcn_rcpf(x);
#else
  return 1.0f / x;
#endif
}

// ws layout (floats): [0:64] M0, [64:128] M1,
// [128..135] Sx0,Sx1,Sy0,Sy1,Sb0,Sb1,C00,C01.
__global__ void setup_consts(const float* __restrict__ Wgoal,
                             const float* __restrict__ bgoal,
                             const float* __restrict__ Wh2p,
                             const float* __restrict__ bh2p,
                             const float* __restrict__ Wabs,
                             const float* __restrict__ babs,
                             float* __restrict__ wsf) {
  const int tid = threadIdx.x;
  const int wv = tid >> 6;
  const int lane = tid & 63;
  if (wv == 0) {
    const int k = lane;
    float s0 = 0.f, s1 = 0.f;
#pragma unroll 8
    for (int jj = 0; jj < 64; ++jj) {
      float wg = Wgoal[jj * 64 + k];
      s0 += wg * Wh2p[128 + jj];
      s1 += wg * Wh2p[320 + jj];
    }
    wsf[k] = s0;
    wsf[64 + k] = s1;
  } else {
    const int i = lane >> 3, sub = lane & 7;
    const int p = i & 1, grp = i >> 1;
    float s = 0.f;
#pragma unroll
    for (int t = 0; t < 8; ++t) {
      int j = sub * 8 + t;
      float wv_ = (grp < 3) ? Wh2p[p * 192 + 64 + j] : Wh2p[p * 192 + 128 + j];
      float av = (grp == 0)   ? Wabs[j * 2 + 0]
                 : (grp == 1) ? Wabs[j * 2 + 1]
                 : (grp == 2) ? babs[j]
                              : bgoal[j];
      s += av * wv_;
    }
    s += __shfl_xor(s, 1, 64);
    s += __shfl_xor(s, 2, 64);
    s += __shfl_xor(s, 4, 64);
    if (sub == 0) {
      if (grp == 2) s += bh2p[p];
      wsf[128 + i] = s;
    }
  }
}

__global__ __launch_bounds__(512, 4) void lstm_mfma(
    const float* __restrict__ tabs, const float* __restrict__ trel,
    const float* __restrict__ h0, const float* __restrict__ c0,
    const float* __restrict__ goals, const float* __restrict__ Wih,
    const float* __restrict__ Whh, const float* __restrict__ bih,
    const float* __restrict__ bhh, const float* __restrict__ Wse,
    const float* __restrict__ bse, const float* __restrict__ Wh2p,
    const float* __restrict__ wsf, float* __restrict__ outp) {
  const int lane = threadIdx.x & 63;
  const int w = threadIdx.x >> 6;  // wave = tile owner (0..7)
  const int q = lane >> 4;
  const int n = lane & 15;
  const int pm = n & 3;  // replicated rel/goal A-row selector
  const int bb = blockIdx.x * (16 * WPB) + 16 * w;  // this wave's batch base

  // LDS: frag-major weights (48 frags x 1KB) + per-wave frag-major h scratch
  // (2 frags x 1KB per wave). Total 48 + 16 = 64KB -> 2 blocks/CU.
  __shared__ __align__(16) _Float16 wfrag[48 * 512];
  __shared__ __align__(16) _Float16 hscr[WPB * 2 * 512];

  const float SI = -1.4426950408889634f;
  const float SG = 2.8853900817779268f;

  // ---- weight frag init (once). Frag f = (g*4 + s)*3 + which:
  // which 0/1 = Whh k-window 0-31 / 32-63 (A[row=16s+n][k=8q+j]),
  // which 2 = x-window (kx=8q+j; slots 16=bias, 17/18 = 0.505 rank-2 fold).
  // i,f,o prescaled by -log2e; g by +2log2e (accs exp2-ready).
  for (int f = (int)(threadIdx.x >> 6); f < 48; f += 8) {
    const int which = f % 3, gs = f / 3;
    const int g = gs >> 2, s = gs & 3;
    const int row = g * 64 + 16 * s + n;
    const float sc = (g == 2) ? SG : SI;
    f16x8 v;
    if (which < 2) {
#pragma unroll
      for (int j = 0; j < 8; ++j)
        v[j] = (_Float16)(sc * Whh[row * 64 + which * 32 + 8 * q + j]);
    } else {
      float bfold = 0.f, m20 = 0.f, m21 = 0.f;
#pragma unroll
      for (int k = 0; k < 16; ++k) {
        float wik = Wih[row * 16 + k];
        bfold += bse[k] * wik;
        m20 += Wse[k * 2 + 0] * wik;
        m21 += Wse[k * 2 + 1] * wik;
      }
      const float bias = sc * (bih[row] + bhh[row] + 0.505f * bfold);
#pragma unroll
      for (int j = 0; j < 8; ++j) {
        const int kx = 8 * q + j;
        float vv;
        if (kx < 16)
          vv = sc * Wih[row * 16 + kx];  // pairs with 0.495|u|
        else if (kx == 16)
          vv = bias;  // pairs with B=1
        else if (kx == 17)
          vv = sc * 0.505f * m20;  // pairs with B=rel0
        else if (kx == 18)
          vv = sc * 0.505f * m21;  // pairs with B=rel1
        else
          vv = 0.f;
        v[j] = (_Float16)vv;
      }
    }
    *(f16x8*)(wfrag + f * 512 + lane * 8) = v;
  }

  // ---- rel projection A-frags, replicated rows m&3<2 (registers) ----
  f16x8 awp0, awp1;
#pragma unroll
  for (int j = 0; j < 8; ++j) {
    float v0 = (pm < 2) ? Wh2p[pm * 192 + q * 8 + j] : 0.f;
    float v1 = (pm < 2) ? Wh2p[pm * 192 + 32 + q * 8 + j] : 0.f;
    awp0[j] = (_Float16)v0;
    awp1[j] = (_Float16)v1;
  }
  const float Sx0 = wsf[128], Sx1 = wsf[129];
  const float Sy0 = wsf[130], Sy1 = wsf[131];

  // ---- Wse consts (pre-scaled by 0.495) as pk pairs ----
  f16x2 wsaP[4], wsbP[4], bscP[4];
  const uint32_t xmask = (q < 2) ? 0x7FFF7FFFu : 0xFFFFFFFFu;
#pragma unroll
  for (int jj = 0; jj < 4; ++jj) {
    f16x2 z = f16x2{(_Float16)0.f, (_Float16)0.f};
    if (q < 2) {
      int kx = q * 8 + 2 * jj;
      wsaP[jj] = f16x2{(_Float16)(0.495f * Wse[kx * 2 + 0]),
                       (_Float16)(0.495f * Wse[kx * 2 + 2])};
      wsbP[jj] = f16x2{(_Float16)(0.495f * Wse[kx * 2 + 1]),
                       (_Float16)(0.495f * Wse[kx * 2 + 3])};
      bscP[jj] = f16x2{(_Float16)(0.495f * bse[kx]),
                       (_Float16)(0.495f * bse[kx + 1])};
    } else if (q == 2 && jj == 0) {
      wsaP[jj] = f16x2{(_Float16)0.f, (_Float16)1.f};  // t = {1, r0}
      wsbP[jj] = z;
      bscP[jj] = f16x2{(_Float16)1.f, (_Float16)0.f};
    } else if (q == 2 && jj == 1) {
      wsaP[jj] = z;  // t = {r1, 0}
      wsbP[jj] = f16x2{(_Float16)1.f, (_Float16)0.f};
      bscP[jj] = z;
    } else {
      wsaP[jj] = z;
      wsbP[jj] = z;
      bscP[jj] = z;
    }
  }

  auto build_x = [&](float r0f, float r1f) -> f16x8 {
    f16x2 r0h = f16x2{(_Float16)r0f, (_Float16)r0f};
    f16x2 r1h = f16x2{(_Float16)r1f, (_Float16)r1f};
    f16x8 xr;
#pragma unroll
    for (int jj = 0; jj < 4; ++jj) {
      f16x2 t = r0h * wsaP[jj] + (r1h * wsbP[jj] + bscP[jj]);
      uint32_t tu = __builtin_bit_cast(uint32_t, t) & xmask;
      f16x2 lr = __builtin_bit_cast(f16x2, tu);
      xr[2 * jj] = lr[0];
      xr[2 * jj + 1] = lr[1];
    }
    return xr;
  };

  const f32x4 zC = {0.f, 0.f, 0.f, 0.f};
  const int wb = w * 1024;  // this wave's h scratch base (f16 units)

  // ---- per-wave tile state ----
  float Gg0, Gg1, ax, ay;
  float cst[4][4];  // [slice s4][reg] = c[batch n][hidden 16*s4+4*q+reg]
  f16x8 xf;
  {
    f16x8 aM0, aM1, bg0, bg1;
#pragma unroll
    for (int j = 0; j < 8; ++j) {
      int k = q * 8 + j;
      aM0[j] = (_Float16)((pm < 2) ? wsf[pm * 64 + k] : 0.f);
      aM1[j] = (_Float16)((pm < 2) ? wsf[pm * 64 + 32 + k] : 0.f);
      bg0[j] = (_Float16)goals[(bb + n) * 64 + k];
      bg1[j] = (_Float16)goals[(bb + n) * 64 + 32 + k];
    }
    f32x4 Ga = __builtin_amdgcn_mfma_f32_16x16x32_f16(aM0, bg0, zC, 0, 0, 0);
    Ga = __builtin_amdgcn_mfma_f32_16x16x32_f16(aM1, bg1, Ga, 0, 0, 0);
    Gg0 = Ga[0] + wsf[132] + wsf[134];
    Gg1 = Ga[1] + wsf[133] + wsf[135];

    ax = tabs[(bb + n) * 2 + 0];
    ay = tabs[(bb + n) * 2 + 1];
    // h0 into frag-major scratch: each lane fills its OWN reader slot.
#pragma unroll
    for (int t = 0; t < 2; ++t) {
      f16x8 hv;
#pragma unroll
      for (int j = 0; j < 8; ++j)
        hv[j] = (_Float16)h0[(bb + n) * 64 + 32 * t + 8 * q + j];
      *(f16x8*)(hscr + wb + t * 512 + lane * 8) = hv;
    }
    // c0: lane holds c[batch n][hidden 16*s4+4*q+reg] (float4 loads).
#pragma unroll
    for (int s4 = 0; s4 < 4; ++s4) {
      const float4 cv =
          *(const float4*)(c0 + (size_t)(bb + n) * 64 + 16 * s4 + 4 * q);
      cst[s4][0] = cv.x;
      cst[s4][1] = cv.y;
      cst[s4][2] = cv.z;
      cst[s4][3] = cv.w;
    }
    xf = build_x(trel[(bb + n) * 2 + 0], trel[(bb + n) * 2 + 1]);
  }

  __syncthreads();  // weight frags staged; ONLY barrier in the kernel

  // frag-major pointers: reads are base + compile-time immediates.
  const _Float16* wfp = wfrag + lane * 8;
  // h write slot: hidden k''=16*s4+4*q+reg -> reader (q'=2*(s4&1)+(q>>1),
  // j=4*(q&1)+reg, frag t=s4>>1) => addr = wwo + s4*256 (f16 units).
  const int wwo = wb + 128 * (q >> 1) + 8 * n + 4 * (q & 1);
  const float K2 = 2.8853900817779268f;

  for (int s = 0; s <= SEQL; ++s) {
    // h_s B-frags from own scratch: contiguous-16B, conflict-free.
    const f16x8 ah0 = *(const f16x8*)(hscr + wb + lane * 8);
    const f16x8 ah1 = *(const f16x8*)(hscr + wb + 512 + lane * 8);

    if (s > 0) {
      // rel_{s-1}: D[p][batch], regs 0,1 valid on every quad -> lane-local.
      f32x4 p = __builtin_amdgcn_mfma_f32_16x16x32_f16(awp0, ah0, zC, 0, 0, 0);
      p = __builtin_amdgcn_mfma_f32_16x16x32_f16(awp1, ah1, p, 0, 0, 0);
      float u0 = p[0] + Gg0 + fmaf(ax, Sx0, ay * Sy0);
      float u1 = p[1] + Gg1 + fmaf(ax, Sx1, ay * Sy1);
      ax += u0;
      ay += u1;
      if (lane < 16) {
        float2 v;
        v.x = u0;
        v.y = u1;
        ((float2*)outp)[(size_t)(s - 1) * B_TOT + bb + lane] = v;
      }
      xf = build_x(u0, u1);
    }

    if (s < SEQL) {
      // ---- slice PAIRS: per pair, wide MFMA phase (8 indep 3-chains,
      // acc[2][4] = 32 regs) then wide nonlin phase (4 indep exp2 streams).
#pragma unroll
      for (int p2 = 0; p2 < 2; ++p2) {
        f32x4 acc[2][4];
#pragma unroll
        for (int u = 0; u < 2; ++u) {
          const int s4 = 2 * p2 + u;
#pragma unroll
          for (int g = 0; g < 4; ++g) {
            const f16x8 w0 =
                *(const f16x8*)(wfp + (12 * g + 3 * s4 + 0) * 512);
            const f16x8 w1 =
                *(const f16x8*)(wfp + (12 * g + 3 * s4 + 1) * 512);
            const f16x8 w2 =
                *(const f16x8*)(wfp + (12 * g + 3 * s4 + 2) * 512);
            f32x4 a = __builtin_amdgcn_mfma_f32_16x16x32_f16(w0, ah0, zC,
                                                             0, 0, 0);
            a = __builtin_amdgcn_mfma_f32_16x16x32_f16(w1, ah1, a, 0, 0, 0);
            a = __builtin_amdgcn_mfma_f32_16x16x32_f16(w2, xf, a, 0, 0, 0);
            acc[u][g] = a;
          }
        }
        // acc0=-i*log2e, acc1=-f*log2e, acc2=2g*log2e, acc3=-o*log2e.
#pragma unroll
        for (int u = 0; u < 2; ++u) {
          const int s4 = 2 * p2 + u;
          f16x4 hp;
#pragma unroll
          for (int pr = 0; pr < 2; ++pr) {
            const int ra = 2 * pr, rb = 2 * pr + 1;
            f32x2 Av = {fexp2(acc[u][0][ra]), fexp2(acc[u][0][rb])};
            f32x2 Fv = {fexp2(acc[u][1][ra]), fexp2(acc[u][1][rb])};
            f32x2 Bv = {fexp2(acc[u][2][ra]), fexp2(acc[u][2][rb])};
            const f32x2 one = {1.f, 1.f};
            f32x2 t1 = Av + one;
            f32x2 t2 = Bv + one;
            f32x2 t3 = Fv + one;
            f32x2 t4 = Bv - one;
            f32x2 m1 = t1 * t2;
            f32x2 cs = {cst[s4][ra], cst[s4][rb]};
            f32x2 num = cs * m1 + t4 * t3;
            f32x2 den = m1 * t3;
            float Rc = frcp(den[0] * den[1]);
            float cc0 = num[0] * den[1] * Rc;
            float cc1 = num[1] * den[0] * Rc;
            cst[s4][ra] = cc0;
            cst[s4][rb] = cc1;
            f32x2 Cv = {fexp2(acc[u][3][ra]), fexp2(acc[u][3][rb])};
            f32x2 Dv = {fexp2(K2 * cc0), fexp2(K2 * cc1)};
            f32x2 hd = (Cv + one) * (Dv + one);
            f32x2 hnm = Dv - one;
            float Rh = frcp(hd[0] * hd[1]);
            hp[ra] = (_Float16)(hnm[0] * hd[1] * Rh);
            hp[rb] = (_Float16)(hnm[1] * hd[0] * Rh);
          }
          *(f16x4*)(hscr + wwo + s4 * 256) = hp;  // one ds_write_b64
        }
      }
    }
  }
}

extern "C" void kernel_launch(void* const* d_in, const int* in_sizes, int n_in,
                              void* d_out, int out_size, void* d_ws,
                              size_t ws_size, hipStream_t stream) {
  (void)in_sizes; (void)n_in; (void)out_size; (void)ws_size;
  const float* tabs  = (const float*)d_in[0];
  const float* trel  = (const float*)d_in[1];
  const float* h0    = (const float*)d_in[2];
  const float* c0    = (const float*)d_in[3];
  const float* goals = (const float*)d_in[4];
  const float* Wih   = (const float*)d_in[5];
  const float* Whh   = (const float*)d_in[6];
  const float* bih   = (const float*)d_in[7];
  const float* bhh   = (const float*)d_in[8];
  const float* Wse   = (const float*)d_in[9];
  const float* bse   = (const float*)d_in[10];
  const float* Wh2p  = (const float*)d_in[11];
  const float* bh2p  = (const float*)d_in[12];
  const float* Wgoal = (const float*)d_in[13];
  const float* bgoal = (const float*)d_in[14];
  const float* Wabs  = (const float*)d_in[15];
  const float* babs  = (const float*)d_in[16];
  float* wsf = (float*)d_ws;

  setup_consts<<<dim3(1), dim3(128), 0, stream>>>(Wgoal, bgoal, Wh2p, bh2p,
                                                  Wabs, babs, wsf);
  lstm_mfma<<<dim3(B_TOT / (16 * WPB)), dim3(512), 0, stream>>>(
      tabs, trel, h0, c0, goals, Wih, Whh, bih, bhh, Wse, bse, Wh2p, wsf,
      (float*)d_out);
}

// Round 11
// 433.254 us; speedup vs baseline: 1.0768x; 1.0768x over previous
//
#include <hip/hip_runtime.h>
#include <stdint.h>

// GoalDecoderLSTM: B=131072 indep LSTM decoders, H=64, E=16, SEQ=30. f32 I/O.
// R17: persistent wave de-phasing. R16 post-mortem: spill-free pair-split =
// session best 339us, but per-wave accounting shows each wave stalls ~84% of
// its step (VALU issue ~2.1k of 13.6k cyc) while the port sits at 63%.
// Hypothesis: PHASE-LOCKING -- identical zero-barrier waves saturate the
// trans pipe together (progressing in lockstep at 1/4 speed = stable
// attractor), then all enter the MFMA/LDS-latency window together -> aligned
// idle. Fix: one-time staggered s_sleep after the weight barrier; with zero
// loop barriers the skew PERSISTS all 30 steps. phase = (w>>2)+2*(blk&1)
// in {0..3}, ~3.4k cyc apart (~1/4 step) -> co-resident waves' trans bursts
// fill each other's latency windows. Discriminating experiment: helps =>
// phase-lock confirmed; flat => trans-pipe roofline.
// Kept (R16): pair-split breadth acc[2][4], autonomous waves (zero loop
// barriers), frag-major conflict-free weights, operand-swapped gates
// (D[hidden][batch], b64 h-writeback), prescaled gate weights
// (-log2e/+2log2e), lrelu rank-2 fold (kx 16..18), all-quad rel, f32x2
// nonlinearity + pair-rcp.

#define B_TOT 131072
#define SEQL 30
#define WPB 8  // waves per block = tiles per block

typedef _Float16 f16x8 __attribute__((ext_vector_type(8)));
typedef _Float16 f16x4 __attribute__((ext_vector_type(4)));
typedef _Float16 f16x2 __attribute__((ext_vector_type(2)));
typedef float f32x4 __attribute__((ext_vector_type(4)));
typedef float f32x2 __attribute__((ext_vector_type(2)));

__device__ __forceinline__ float fexp2(float x) {
#if __has_builtin(__builtin_amdgcn_exp2f)
  return __builtin_amdgcn_exp2f(x);
#else
  return exp2f(x);
#endif
}
__device__ __forceinline__ float frcp(float x) {
#if __has_builtin(__builtin_amdgcn_rcpf)
  return __builtin_amdgcn_rcpf(x);
#else
  return 1.0f / x;
#endif
}

// ws layout (floats): [0:64] M0, [64:128] M1,
// [128..135] Sx0,Sx1,Sy0,Sy1,Sb0,Sb1,C00,C01.
__global__ void setup_consts(const float* __restrict__ Wgoal,
                             const float* __restrict__ bgoal,
                             const float* __restrict__ Wh2p,
                             const float* __restrict__ bh2p,
                             const float* __restrict__ Wabs,
                             const float* __restrict__ babs,
                             float* __restrict__ wsf) {
  const int tid = threadIdx.x;
  const int wv = tid >> 6;
  const int lane = tid & 63;
  if (wv == 0) {
    const int k = lane;
    float s0 = 0.f, s1 = 0.f;
#pragma unroll 8
    for (int jj = 0; jj < 64; ++jj) {
      float wg = Wgoal[jj * 64 + k];
      s0 += wg * Wh2p[128 + jj];
      s1 += wg * Wh2p[320 + jj];
    }
    wsf[k] = s0;
    wsf[64 + k] = s1;
  } else {
    const int i = lane >> 3, sub = lane & 7;
    const int p = i & 1, grp = i >> 1;
    float s = 0.f;
#pragma unroll
    for (int t = 0; t < 8; ++t) {
      int j = sub * 8 + t;
      float wv_ = (grp < 3) ? Wh2p[p * 192 + 64 + j] : Wh2p[p * 192 + 128 + j];
      float av = (grp == 0)   ? Wabs[j * 2 + 0]
                 : (grp == 1) ? Wabs[j * 2 + 1]
                 : (grp == 2) ? babs[j]
                              : bgoal[j];
      s += av * wv_;
    }
    s += __shfl_xor(s, 1, 64);
    s += __shfl_xor(s, 2, 64);
    s += __shfl_xor(s, 4, 64);
    if (sub == 0) {
      if (grp == 2) s += bh2p[p];
      wsf[128 + i] = s;
    }
  }
}

__global__ __launch_bounds__(512, 4) void lstm_mfma(
    const float* __restrict__ tabs, const float* __restrict__ trel,
    const float* __restrict__ h0, const float* __restrict__ c0,
    const float* __restrict__ goals, const float* __restrict__ Wih,
    const float* __restrict__ Whh, const float* __restrict__ bih,
    const float* __restrict__ bhh, const float* __restrict__ Wse,
    const float* __restrict__ bse, const float* __restrict__ Wh2p,
    const float* __restrict__ wsf, float* __restrict__ outp) {
  const int lane = threadIdx.x & 63;
  const int w = threadIdx.x >> 6;  // wave = tile owner (0..7)
  const int q = lane >> 4;
  const int n = lane & 15;
  const int pm = n & 3;  // replicated rel/goal A-row selector
  const int bb = blockIdx.x * (16 * WPB) + 16 * w;  // this wave's batch base

  // LDS: frag-major weights (48 frags x 1KB) + per-wave frag-major h scratch
  // (2 frags x 1KB per wave). Total 48 + 16 = 64KB -> 2 blocks/CU.
  __shared__ __align__(16) _Float16 wfrag[48 * 512];
  __shared__ __align__(16) _Float16 hscr[WPB * 2 * 512];

  const float SI = -1.4426950408889634f;
  const float SG = 2.8853900817779268f;

  // ---- weight frag init (once). Frag f = (g*4 + s)*3 + which:
  // which 0/1 = Whh k-window 0-31 / 32-63 (A[row=16s+n][k=8q+j]),
  // which 2 = x-window (kx=8q+j; slots 16=bias, 17/18 = 0.505 rank-2 fold).
  // i,f,o prescaled by -log2e; g by +2log2e (accs exp2-ready).
  for (int f = (int)(threadIdx.x >> 6); f < 48; f += 8) {
    const int which = f % 3, gs = f / 3;
    const int g = gs >> 2, s = gs & 3;
    const int row = g * 64 + 16 * s + n;
    const float sc = (g == 2) ? SG : SI;
    f16x8 v;
    if (which < 2) {
#pragma unroll
      for (int j = 0; j < 8; ++j)
        v[j] = (_Float16)(sc * Whh[row * 64 + which * 32 + 8 * q + j]);
    } else {
      float bfold = 0.f, m20 = 0.f, m21 = 0.f;
#pragma unroll
      for (int k = 0; k < 16; ++k) {
        float wik = Wih[row * 16 + k];
        bfold += bse[k] * wik;
        m20 += Wse[k * 2 + 0] * wik;
        m21 += Wse[k * 2 + 1] * wik;
      }
      const float bias = sc * (bih[row] + bhh[row] + 0.505f * bfold);
#pragma unroll
      for (int j = 0; j < 8; ++j) {
        const int kx = 8 * q + j;
        float vv;
        if (kx < 16)
          vv = sc * Wih[row * 16 + kx];  // pairs with 0.495|u|
        else if (kx == 16)
          vv = bias;  // pairs with B=1
        else if (kx == 17)
          vv = sc * 0.505f * m20;  // pairs with B=rel0
        else if (kx == 18)
          vv = sc * 0.505f * m21;  // pairs with B=rel1
        else
          vv = 0.f;
        v[j] = (_Float16)vv;
      }
    }
    *(f16x8*)(wfrag + f * 512 + lane * 8) = v;
  }

  // ---- rel projection A-frags, replicated rows m&3<2 (registers) ----
  f16x8 awp0, awp1;
#pragma unroll
  for (int j = 0; j < 8; ++j) {
    float v0 = (pm < 2) ? Wh2p[pm * 192 + q * 8 + j] : 0.f;
    float v1 = (pm < 2) ? Wh2p[pm * 192 + 32 + q * 8 + j] : 0.f;
    awp0[j] = (_Float16)v0;
    awp1[j] = (_Float16)v1;
  }
  const float Sx0 = wsf[128], Sx1 = wsf[129];
  const float Sy0 = wsf[130], Sy1 = wsf[131];

  // ---- Wse consts (pre-scaled by 0.495) as pk pairs ----
  f16x2 wsaP[4], wsbP[4], bscP[4];
  const uint32_t xmask = (q < 2) ? 0x7FFF7FFFu : 0xFFFFFFFFu;
#pragma unroll
  for (int jj = 0; jj < 4; ++jj) {
    f16x2 z = f16x2{(_Float16)0.f, (_Float16)0.f};
    if (q < 2) {
      int kx = q * 8 + 2 * jj;
      wsaP[jj] = f16x2{(_Float16)(0.495f * Wse[kx * 2 + 0]),
                       (_Float16)(0.495f * Wse[kx * 2 + 2])};
      wsbP[jj] = f16x2{(_Float16)(0.495f * Wse[kx * 2 + 1]),
                       (_Float16)(0.495f * Wse[kx * 2 + 3])};
      bscP[jj] = f16x2{(_Float16)(0.495f * bse[kx]),
                       (_Float16)(0.495f * bse[kx + 1])};
    } else if (q == 2 && jj == 0) {
      wsaP[jj] = f16x2{(_Float16)0.f, (_Float16)1.f};  // t = {1, r0}
      wsbP[jj] = z;
      bscP[jj] = f16x2{(_Float16)1.f, (_Float16)0.f};
    } else if (q == 2 && jj == 1) {
      wsaP[jj] = z;  // t = {r1, 0}
      wsbP[jj] = f16x2{(_Float16)1.f, (_Float16)0.f};
      bscP[jj] = z;
    } else {
      wsaP[jj] = z;
      wsbP[jj] = z;
      bscP[jj] = z;
    }
  }

  auto build_x = [&](float r0f, float r1f) -> f16x8 {
    f16x2 r0h = f16x2{(_Float16)r0f, (_Float16)r0f};
    f16x2 r1h = f16x2{(_Float16)r1f, (_Float16)r1f};
    f16x8 xr;
#pragma unroll
    for (int jj = 0; jj < 4; ++jj) {
      f16x2 t = r0h * wsaP[jj] + (r1h * wsbP[jj] + bscP[jj]);
      uint32_t tu = __builtin_bit_cast(uint32_t, t) & xmask;
      f16x2 lr = __builtin_bit_cast(f16x2, tu);
      xr[2 * jj] = lr[0];
      xr[2 * jj + 1] = lr[1];
    }
    return xr;
  };

  const f32x4 zC = {0.f, 0.f, 0.f, 0.f};
  const int wb = w * 1024;  // this wave's h scratch base (f16 units)

  // ---- per-wave tile state ----
  float Gg0, Gg1, ax, ay;
  float cst[4][4];  // [slice s4][reg] = c[batch n][hidden 16*s4+4*q+reg]
  f16x8 xf;
  {
    f16x8 aM0, aM1, bg0, bg1;
#pragma unroll
    for (int j = 0; j < 8; ++j) {
      int k = q * 8 + j;
      aM0[j] = (_Float16)((pm < 2) ? wsf[pm * 64 + k] : 0.f);
      aM1[j] = (_Float16)((pm < 2) ? wsf[pm * 64 + 32 + k] : 0.f);
      bg0[j] = (_Float16)goals[(bb + n) * 64 + k];
      bg1[j] = (_Float16)goals[(bb + n) * 64 + 32 + k];
    }
    f32x4 Ga = __builtin_amdgcn_mfma_f32_16x16x32_f16(aM0, bg0, zC, 0, 0, 0);
    Ga = __builtin_amdgcn_mfma_f32_16x16x32_f16(aM1, bg1, Ga, 0, 0, 0);
    Gg0 = Ga[0] + wsf[132] + wsf[134];
    Gg1 = Ga[1] + wsf[133] + wsf[135];

    ax = tabs[(bb + n) * 2 + 0];
    ay = tabs[(bb + n) * 2 + 1];
    // h0 into frag-major scratch: each lane fills its OWN reader slot.
#pragma unroll
    for (int t = 0; t < 2; ++t) {
      f16x8 hv;
#pragma unroll
      for (int j = 0; j < 8; ++j)
        hv[j] = (_Float16)h0[(bb + n) * 64 + 32 * t + 8 * q + j];
      *(f16x8*)(hscr + wb + t * 512 + lane * 8) = hv;
    }
    // c0: lane holds c[batch n][hidden 16*s4+4*q+reg] (float4 loads).
#pragma unroll
    for (int s4 = 0; s4 < 4; ++s4) {
      const float4 cv =
          *(const float4*)(c0 + (size_t)(bb + n) * 64 + 16 * s4 + 4 * q);
      cst[s4][0] = cv.x;
      cst[s4][1] = cv.y;
      cst[s4][2] = cv.z;
      cst[s4][3] = cv.w;
    }
    xf = build_x(trel[(bb + n) * 2 + 0], trel[(bb + n) * 2 + 1]);
  }

  __syncthreads();  // weight frags staged; ONLY barrier in the kernel

  // ---- persistent de-phasing: skew co-resident waves by ~1/4 step each.
  // SIMD residents are waves {w, w+4} from 2 blocks -> phase 0..3 mostly
  // distinct. Zero loop barriers => skew persists all 30 steps.
  {
    const int phase = (w >> 2) + 2 * (int)(blockIdx.x & 1);
    for (int i = 0; i < phase; ++i) __builtin_amdgcn_s_sleep(53);  // ~3.4k cyc
  }

  // frag-major pointers: reads are base + compile-time immediates.
  const _Float16* wfp = wfrag + lane * 8;
  // h write slot: hidden k''=16*s4+4*q+reg -> reader (q'=2*(s4&1)+(q>>1),
  // j=4*(q&1)+reg, frag t=s4>>1) => addr = wwo + s4*256 (f16 units).
  const int wwo = wb + 128 * (q >> 1) + 8 * n + 4 * (q & 1);
  const float K2 = 2.8853900817779268f;

  for (int s = 0; s <= SEQL; ++s) {
    // h_s B-frags from own scratch: contiguous-16B, conflict-free.
    const f16x8 ah0 = *(const f16x8*)(hscr + wb + lane * 8);
    const f16x8 ah1 = *(const f16x8*)(hscr + wb + 512 + lane * 8);

    if (s > 0) {
      // rel_{s-1}: D[p][batch], regs 0,1 valid on every quad -> lane-local.
      f32x4 p = __builtin_amdgcn_mfma_f32_16x16x32_f16(awp0, ah0, zC, 0, 0, 0);
      p = __builtin_amdgcn_mfma_f32_16x16x32_f16(awp1, ah1, p, 0, 0, 0);
      float u0 = p[0] + Gg0 + fmaf(ax, Sx0, ay * Sy0);
      float u1 = p[1] + Gg1 + fmaf(ax, Sx1, ay * Sy1);
      ax += u0;
      ay += u1;
      if (lane < 16) {
        float2 v;
        v.x = u0;
        v.y = u1;
        ((float2*)outp)[(size_t)(s - 1) * B_TOT + bb + lane] = v;
      }
      xf = build_x(u0, u1);
    }

    if (s < SEQL) {
      // ---- slice PAIRS: per pair, wide MFMA phase (8 indep 3-chains,
      // acc[2][4] = 32 regs) then wide nonlin phase (4 indep exp2 streams).
#pragma unroll
      for (int p2 = 0; p2 < 2; ++p2) {
        f32x4 acc[2][4];
#pragma unroll
        for (int u = 0; u < 2; ++u) {
          const int s4 = 2 * p2 + u;
#pragma unroll
          for (int g = 0; g < 4; ++g) {
            const f16x8 w0 =
                *(const f16x8*)(wfp + (12 * g + 3 * s4 + 0) * 512);
            const f16x8 w1 =
                *(const f16x8*)(wfp + (12 * g + 3 * s4 + 1) * 512);
            const f16x8 w2 =
                *(const f16x8*)(wfp + (12 * g + 3 * s4 + 2) * 512);
            f32x4 a = __builtin_amdgcn_mfma_f32_16x16x32_f16(w0, ah0, zC,
                                                             0, 0, 0);
            a = __builtin_amdgcn_mfma_f32_16x16x32_f16(w1, ah1, a, 0, 0, 0);
            a = __builtin_amdgcn_mfma_f32_16x16x32_f16(w2, xf, a, 0, 0, 0);
            acc[u][g] = a;
          }
        }
        // acc0=-i*log2e, acc1=-f*log2e, acc2=2g*log2e, acc3=-o*log2e.
#pragma unroll
        for (int u = 0; u < 2; ++u) {
          const int s4 = 2 * p2 + u;
          f16x4 hp;
#pragma unroll
          for (int pr = 0; pr < 2; ++pr) {
            const int ra = 2 * pr, rb = 2 * pr + 1;
            f32x2 Av = {fexp2(acc[u][0][ra]), fexp2(acc[u][0][rb])};
            f32x2 Fv = {fexp2(acc[u][1][ra]), fexp2(acc[u][1][rb])};
            f32x2 Bv = {fexp2(acc[u][2][ra]), fexp2(acc[u][2][rb])};
            const f32x2 one = {1.f, 1.f};
            f32x2 t1 = Av + one;
            f32x2 t2 = Bv + one;
            f32x2 t3 = Fv + one;
            f32x2 t4 = Bv - one;
            f32x2 m1 = t1 * t2;
            f32x2 cs = {cst[s4][ra], cst[s4][rb]};
            f32x2 num = cs * m1 + t4 * t3;
            f32x2 den = m1 * t3;
            float Rc = frcp(den[0] * den[1]);
            float cc0 = num[0] * den[1] * Rc;
            float cc1 = num[1] * den[0] * Rc;
            cst[s4][ra] = cc0;
            cst[s4][rb] = cc1;
            f32x2 Cv = {fexp2(acc[u][3][ra]), fexp2(acc[u][3][rb])};
            f32x2 Dv = {fexp2(K2 * cc0), fexp2(K2 * cc1)};
            f32x2 hd = (Cv + one) * (Dv + one);
            f32x2 hnm = Dv - one;
            float Rh = frcp(hd[0] * hd[1]);
            hp[ra] = (_Float16)(hnm[0] * hd[1] * Rh);
            hp[rb] = (_Float16)(hnm[1] * hd[0] * Rh);
          }
          *(f16x4*)(hscr + wwo + s4 * 256) = hp;  // one ds_write_b64
        }
      }
    }
  }
}

extern "C" void kernel_launch(void* const* d_in, const int* in_sizes, int n_in,
                              void* d_out, int out_size, void* d_ws,
                              size_t ws_size, hipStream_t stream) {
  (void)in_sizes; (void)n_in; (void)out_size; (void)ws_size;
  const float* tabs  = (const float*)d_in[0];
  const float* trel  = (const float*)d_in[1];
  const float* h0    = (const float*)d_in[2];
  const float* c0    = (const float*)d_in[3];
  const float* goals = (const float*)d_in[4];
  const float* Wih   = (const float*)d_in[5];
  const float* Whh   = (const float*)d_in[6];
  const float* bih   = (const float*)d_in[7];
  const float* bhh   = (const float*)d_in[8];
  const float* Wse   = (const float*)d_in[9];
  const float* bse   = (const float*)d_in[10];
  const float* Wh2p  = (const float*)d_in[11];
  const float* bh2p  = (const float*)d_in[12];
  const float* Wgoal = (const float*)d_in[13];
  const float* bgoal = (const float*)d_in[14];
  const float* Wabs  = (const float*)d_in[15];
  const float* babs  = (const float*)d_in[16];
  float* wsf = (float*)d_ws;

  setup_consts<<<dim3(1), dim3(128), 0, stream>>>(Wgoal, bgoal, Wh2p, bh2p,
                                                  Wabs, babs, wsf);
  lstm_mfma<<<dim3(B_TOT / (16 * WPB)), dim3(512), 0, stream>>>(
      tabs, trel, h0, c0, goals, Wih, Whh, bih, bhh, Wse, bse, Wh2p, wsf,
      (float*)d_out);
}